// Round 6
// baseline (307.739 us; speedup 1.0000x reference)
//
#include <hip/hip_runtime.h>

typedef _Float16 f16;
typedef f16 f16x8 __attribute__((ext_vector_type(8)));
typedef float f32x4 __attribute__((ext_vector_type(4)));
typedef float f32x16 __attribute__((ext_vector_type(16)));

#define BATCH   32768
#define NF      162
#define ACCH    1024      // hidden accumulator width (without psqt)
#define KSL     192       // K padded to 192 halfs
#define NKS2    12        // 32x32x16 K-steps per 192
#define NB      8
#define DIVQ    20
#define TM      64        // rows per block
#define NT      512       // threads per block
#define NCH     128       // hidden chunk
#define NCHUNK  (ACCH/NCH) // 8
#define MAXBLK  (BATCH/TM + NB - 1)   // 519

// binning partition
#define BINBLK  256
#define RPB     (BATCH / BINBLK)      // 128 rows per binning block

// workspace layout (bytes)
#define WS_WACC16   0
#define WS_W116     (WS_WACC16 + ACCH*KSL*2)       // 393216
#define WS_BUCKET   (WS_W116 + 256*2048*2)         // 1441792
#define WS_ORDER    (WS_BUCKET + BATCH*4)          // 1572864
#define WS_CNT      (WS_ORDER + BATCH*4)           // 1703936
#define WS_BASE     (WS_CNT + 64)
#define WS_PART     (WS_BASE + 64)                 // BINBLK*8 ints
#define WS_BB       (WS_PART + BINBLK*8*4)         // BINBLK*8 ints
#define WS_BLKMAP   WS_PART                        // reuse: part dead after binsetup reads it

// LDS: Xb 16384 (h1s/h2s alias) + psq 256
#define LDS_BYTES   16640

// ---------------- fused prep + binning ----------------
// blocks [0,256): bucket per row + per-block histogram (no global atomics)
// blocks [256,1024): weights -> f16 fragment-major layouts
// waccF (32x32x16 B-frag): u16 idx = (((c*12+ks)*2 + kh)*128 + n)*8 + e
//   value = Wacc[c*128+n][k], k = ks*16 + kh*8 + e (0 if k>=NF)
// w1F (16x16x32 B-frag): u16 idx = ((((bkt*2+s)*8+c)*16 + ks*4 + l4)*32 + n)*8 + e
//   value = W1[bkt*32+n][s*1024 + c*128 + ks*32 + l4*8 + e]
__global__ __launch_bounds__(512) void k_prepbin(const float* __restrict__ stm,
                                                 const float* __restrict__ Wacc,
                                                 const float* __restrict__ W1,
                                                 int* __restrict__ bucket,
                                                 int* __restrict__ part,
                                                 f16* __restrict__ waccF,
                                                 f16* __restrict__ w1F)
{
    if (blockIdx.x < BINBLK) {
        __shared__ int hist[NB];
        int tid = threadIdx.x;
        if (tid < NB) hist[tid] = 0;
        __syncthreads();
        int wv = tid >> 6, ln = tid & 63;
        int rowbase = blockIdx.x * RPB + wv * (RPB / 8);   // 16 rows per wave
        for (int i = 0; i < RPB / 8; i++) {
            int row = rowbase + i;
            const float* rp = stm + (long)row * NF;
            float s = 0.f;
            for (int k = ln; k < NF; k += 64) s += rp[k];
            for (int off = 32; off > 0; off >>= 1) s += __shfl_down(s, off);
            if (ln == 0) {
                int pc = (int)(s + 0.5f);
                int b = pc / DIVQ; if (b > NB - 1) b = NB - 1;
                bucket[row] = b;
                atomicAdd(&hist[b], 1);
            }
        }
        __syncthreads();
        if (tid < NB) part[blockIdx.x * NB + tid] = hist[tid];
    } else {
        int tid = (blockIdx.x - BINBLK) * blockDim.x + threadIdx.x;
        int stride = (gridDim.x - BINBLK) * blockDim.x;
        // waccF: dest-linear (small, 384 KB)
        for (int t = tid; t < ACCH * KSL; t += stride) {
            int e = t & 7, f = t >> 3;
            int n = f & 127, g = f >> 7;
            int kh = g & 1, h = g >> 1;
            int ks = h % NKS2, c = h / NKS2;
            int k = ks * 16 + kh * 8 + e;
            int row = c * 128 + n;
            waccF[t] = (f16)((k < NF) ? Wacc[row * NF + k] : 0.f);
        }
        // w1F: source-linear coalesced float4 reads, scattered 8B writes
        for (int t4 = tid; t4 < 256 * 2048 / 4; t4 += stride) {
            int t = t4 * 4;
            float4 v = *(const float4*)(W1 + t);
            int n_g = t >> 11, k = t & 2047;
            int bkt = n_g >> 5, n = n_g & 31;
            int s = k >> 10, c = (k >> 7) & 7, ks = (k >> 5) & 3, l4 = (k >> 3) & 3;
            int e = k & 7;   // 0 or 4
            long base = (((((long)(bkt * 2 + s) * 8 + c) * 16 + ks * 4 + l4) * 32 + n) * 8) + e;
            w1F[base + 0] = (f16)v.x;
            w1F[base + 1] = (f16)v.y;
            w1F[base + 2] = (f16)v.z;
            w1F[base + 3] = (f16)v.w;
        }
    }
}

// 8 waves, one per bucket: parallel prefix over 256 per-block partials
__global__ __launch_bounds__(512) void k_binsetup(const int* __restrict__ part,
                                                  int* __restrict__ cnt,
                                                  int* __restrict__ base,
                                                  int* __restrict__ bb,
                                                  int* __restrict__ blkmap)
{
    __shared__ int tot[NB], bas[NB], tstart[NB + 1];
    int tid = threadIdx.x;
    int wv = tid >> 6, ln = tid & 63;
    int b = wv;
    int v0 = part[(ln * 4 + 0) * NB + b];
    int v1 = part[(ln * 4 + 1) * NB + b];
    int v2 = part[(ln * 4 + 2) * NB + b];
    int v3 = part[(ln * 4 + 3) * NB + b];
    int s = v0 + v1 + v2 + v3;
    int inc = s;
    for (int off = 1; off < 64; off <<= 1) {
        int n = __shfl_up(inc, off);
        if (ln >= off) inc += n;
    }
    int exc = inc - s;
    if (ln == 63) tot[b] = inc;
    __syncthreads();
    if (tid == 0) {
        int a = 0;
        for (int q = 0; q < NB; q++) { bas[q] = a; base[q] = a; a += tot[q]; }
        int t = 0;
        for (int q = 0; q < NB; q++) { tstart[q] = t; t += (tot[q] + TM - 1) / TM; }
        tstart[NB] = t;
        for (int q = 0; q < NB; q++) cnt[q] = tot[q];
    }
    __syncthreads();
    int run = exc + bas[b];
    bb[(ln * 4 + 0) * NB + b] = run; run += v0;
    bb[(ln * 4 + 1) * NB + b] = run; run += v1;
    bb[(ln * 4 + 2) * NB + b] = run; run += v2;
    bb[(ln * 4 + 3) * NB + b] = run;
    for (int i = tid; i < MAXBLK; i += 512) {
        int v = -1;
        for (int q = 0; q < NB; q++)
            if (i >= tstart[q] && i < tstart[q + 1]) v = q | ((i - tstart[q]) << 4);
        blkmap[i] = v;
    }
}

__global__ __launch_bounds__(256) void k_binscatter(const int* __restrict__ bucket,
                                                    const int* __restrict__ bb,
                                                    int* __restrict__ order)
{
    __shared__ int lcur[NB];
    int tid = threadIdx.x;
    if (tid < NB) lcur[tid] = bb[blockIdx.x * NB + tid];
    __syncthreads();
    int blkstart = blockIdx.x * RPB;
    for (int i = tid; i < RPB; i += 256) {
        int row = blkstart + i;
        int b = bucket[row];
        int pos = atomicAdd(&lcur[b], 1);
        order[pos] = row;
    }
}

// ---------------- fused main kernel ----------------
// Phase 1: A-panel (features) held in registers across all chunks; B-frags from global.
__global__ __launch_bounds__(NT, 4) void k_main(
    const float* __restrict__ stm, const float* __restrict__ nstm,
    const float* __restrict__ Wacc, const float* __restrict__ bacc,
    const float* __restrict__ b1, const float* __restrict__ W2,
    const float* __restrict__ b2, const float* __restrict__ W3,
    const float* __restrict__ b3,
    const f16* __restrict__ waccF, const f16* __restrict__ w1F,
    const int* __restrict__ cnt, const int* __restrict__ base,
    const int* __restrict__ order, const int* __restrict__ blkmap,
    float* __restrict__ out)
{
    int bm = blkmap[blockIdx.x];
    if (bm < 0) return;
    int bkt = bm & 15, tile = bm >> 4;
    int rowbase = base[bkt] + tile * TM;
    int nrows = cnt[bkt] - tile * TM; if (nrows > TM) nrows = TM;

    extern __shared__ __align__(16) char lds_raw[];
    f16* Xb   = (f16*)lds_raw;                      // [64][128] swizzled
    f16* h1s  = (f16*)lds_raw;                      // [64][40], aliases Xb (after last phase2)
    f16* h2s  = (f16*)(lds_raw + TM * 40 * 2);      // [64][40], aliases Xb
    float* psq = (float*)(lds_raw + TM * NCH * 2);  // [64]

    int tid = threadIdx.x;
    int wv = tid >> 6, ln = tid & 63;
    int l15 = ln & 15, l4 = ln >> 4;
    int l31 = ln & 31, kh = ln >> 5;

    // wave tile assignment
    int wr = wv & 1;    // phase1 row-half (rows wr*32..+32)
    int wc = wv >> 1;   // phase1 col-quarter (cols wc*32..+32)
    int mt = wv >> 1;   // phase2/3: M-tile 0..3
    int nh = wv & 1;    // phase2/3: N-half 0..1

    int myrow = wr * 32 + l31;
    int rowclamp = (myrow < nrows) ? myrow : (nrows - 1);
    int rowidx = order[rowbase + rowclamp];

    int colc = wc * 32 + l31;   // col within chunk (0..127)

    float bb1 = b1[bkt * 32 + nh * 16 + l15];
    f32x4 h1acc; h1acc[0] = h1acc[1] = h1acc[2] = h1acc[3] = bb1;

    const float* psqw = Wacc + (long)ACCH * NF;   // psqt weight row (fp32)
    const f16x8* wfr  = (const f16x8*)waccF;
    const f16x8* w1fr = (const f16x8*)w1F;

    for (int s = 0; s < 2; s++) {
        const float* src = s ? nstm : stm;
        const float* rp = src + (long)rowidx * NF;

        // ---- load A-panel (12 x f16x8 per lane) direct from global + psqt on the fly ----
        f16x8 af[NKS2];
        float pp = 0.f;
        #pragma unroll
        for (int ks = 0; ks < NKS2; ks++) {
            int k0 = ks * 16 + kh * 8;
            float v0=0.f,v1=0.f,v2=0.f,v3=0.f,v4=0.f,v5=0.f,v6=0.f,v7=0.f;
            if (k0 <= 152) {
                float2 a0 = *(const float2*)(rp + k0);
                float2 a1 = *(const float2*)(rp + k0 + 2);
                float2 a2 = *(const float2*)(rp + k0 + 4);
                float2 a3 = *(const float2*)(rp + k0 + 6);
                v0=a0.x; v1=a0.y; v2=a1.x; v3=a1.y;
                v4=a2.x; v5=a2.y; v6=a3.x; v7=a3.y;
                float4 pa = *(const float4*)(psqw + k0);
                float4 pb = *(const float4*)(psqw + k0 + 4);
                pp += v0*pa.x + v1*pa.y + v2*pa.z + v3*pa.w
                    + v4*pb.x + v5*pb.y + v6*pb.z + v7*pb.w;
            } else if (k0 == 160) {
                float2 a0 = *(const float2*)(rp + 160);
                v0 = a0.x; v1 = a0.y;
                pp += v0*psqw[160] + v1*psqw[161];
            }
            f16x8 h;
            h[0]=(f16)v0; h[1]=(f16)v1; h[2]=(f16)v2; h[3]=(f16)v3;
            h[4]=(f16)v4; h[5]=(f16)v5; h[6]=(f16)v6; h[7]=(f16)v7;
            af[ks] = h;
        }
        pp += __shfl_xor(pp, 32);          // combine kh halves: full row dot
        if (wv < 2 && ln < 32) {           // one wave pair owns psq writes
            if (s) psq[wr * 32 + l31] -= 0.5f * pp;
            else   psq[wr * 32 + l31]  = 0.5f * pp;
        }

        for (int c = 0; c < NCHUNK; c++) {
            // ---- phase 1: 32x32 MFMA, A from regs, B from global (L2-hot) ----
            float bias = bacc[c * NCH + colc];
            f32x16 acc;
            #pragma unroll
            for (int q = 0; q < 16; q++) acc[q] = bias;

            const f16x8* wp = wfr + ((c * NKS2) * 2 + kh) * 128 + colc;
            #pragma unroll
            for (int ks = 0; ks < NKS2; ks++) {
                f16x8 bf = wp[ks * 256];
                acc = __builtin_amdgcn_mfma_f32_32x32x16_f16(af[ks], bf, acc, 0, 0, 0);
            }
            __syncthreads();  // Xb free (phase2 readers of prev chunk done)
            // epilogue: clip^2 -> Xb (f16, swizzled)
            #pragma unroll
            for (int reg = 0; reg < 16; reg++) {
                int rr = wr * 32 + 4 * kh + (reg & 3) + 8 * (reg >> 2);
                float v = acc[reg];
                v = fminf(fmaxf(v, 0.f), 1.f);
                v = v * v;
                Xb[rr * NCH + ((((colc >> 3) ^ (rr & 7)) << 3) | (colc & 7))] = (f16)v;
            }
            __syncthreads();  // Xb ready

            // ---- phase 2: h1 += act_chunk @ W1_chunk^T (16x16), B-frags from global ----
            const f16x8* w1p = w1fr + ((bkt * 2 + s) * 8 + c) * 512;
            #pragma unroll
            for (int ks = 0; ks < NCH / 32; ks++) {
                int s0 = ks * 4 + l4;
                int row = mt * 16 + l15;
                f16x8 a = *(const f16x8*)(Xb + row * NCH + ((s0 ^ (row & 7)) << 3));
                f16x8 b = w1p[s0 * 32 + nh * 16 + l15];
                h1acc = __builtin_amdgcn_mfma_f32_16x16x32_f16(a, b, h1acc, 0, 0, 0);
            }
        }
    }

    __syncthreads();  // all phase2 reads of Xb done before h1s overwrite (alias)

    // ---- h1 finalize: clip [0,1] -> h1s ----
    #pragma unroll
    for (int jr = 0; jr < 4; jr++) {
        int row = mt * 16 + l4 * 4 + jr;
        int col = nh * 16 + l15;
        float v = fminf(fmaxf(h1acc[jr], 0.f), 1.f);
        h1s[row * 40 + col] = (f16)v;
    }
    __syncthreads();

    // ---- layer 3: h2 = clip(h1 @ W2_b^T + b2, 0, 1); W2 frag direct from global ----
    {
        int nn = nh * 16 + l15;
        const float* w2r = W2 + (bkt * 32 + nn) * 32;
        float4 wa = *(const float4*)(w2r + l4 * 8);
        float4 wb = *(const float4*)(w2r + l4 * 8 + 4);
        f16x8 bfr;
        bfr[0]=(f16)wa.x; bfr[1]=(f16)wa.y; bfr[2]=(f16)wa.z; bfr[3]=(f16)wa.w;
        bfr[4]=(f16)wb.x; bfr[5]=(f16)wb.y; bfr[6]=(f16)wb.z; bfr[7]=(f16)wb.w;
        int row = mt * 16 + l15;
        f16x8 a = *(const f16x8*)(h1s + row * 40 + l4 * 8);
        float bb2 = b2[bkt * 32 + nn];
        f32x4 acc2; acc2[0] = acc2[1] = acc2[2] = acc2[3] = bb2;
        acc2 = __builtin_amdgcn_mfma_f32_16x16x32_f16(a, bfr, acc2, 0, 0, 0);
        #pragma unroll
        for (int jr = 0; jr < 4; jr++) {
            int r2 = mt * 16 + l4 * 4 + jr;
            float v = fminf(fmaxf(acc2[jr], 0.f), 1.f);
            h2s[r2 * 40 + nn] = (f16)v;
        }
    }
    __syncthreads();

    // ---- layer 4 + psqt -> output ----
    if (tid < nrows) {
        const float* w3r = W3 + bkt * 32;
        float o = b3[bkt] + psq[tid];
        #pragma unroll 8
        for (int n = 0; n < 32; n++) o += (float)h2s[tid * 40 + n] * w3r[n];
        out[order[rowbase + tid]] = o;
    }
}

// ---------------- launcher ----------------
extern "C" void kernel_launch(void* const* d_in, const int* in_sizes, int n_in,
                              void* d_out, int out_size, void* d_ws, size_t ws_size,
                              hipStream_t stream)
{
    (void)in_sizes; (void)n_in; (void)out_size; (void)ws_size;
    const float* stm  = (const float*)d_in[0];
    const float* nstm = (const float*)d_in[1];
    const float* Wacc = (const float*)d_in[2];
    const float* bacc = (const float*)d_in[3];
    const float* W1   = (const float*)d_in[4];
    const float* b1   = (const float*)d_in[5];
    const float* W2   = (const float*)d_in[6];
    const float* b2   = (const float*)d_in[7];
    const float* W3   = (const float*)d_in[8];
    const float* b3   = (const float*)d_in[9];
    float* out = (float*)d_out;

    char* ws = (char*)d_ws;
    f16* waccF  = (f16*)(ws + WS_WACC16);
    f16* w1F    = (f16*)(ws + WS_W116);
    int* bucket = (int*)(ws + WS_BUCKET);
    int* order  = (int*)(ws + WS_ORDER);
    int* cnt    = (int*)(ws + WS_CNT);
    int* basep  = (int*)(ws + WS_BASE);
    int* part   = (int*)(ws + WS_PART);
    int* bb     = (int*)(ws + WS_BB);
    int* blkmap = (int*)(ws + WS_BLKMAP);   // aliases part (dead after binsetup)

    hipLaunchKernelGGL(k_prepbin, dim3(1024), dim3(512), 0, stream,
                       stm, Wacc, W1, bucket, part, waccF, w1F);
    hipLaunchKernelGGL(k_binsetup, dim3(1), dim3(512), 0, stream, part, cnt, basep, bb, blkmap);
    hipLaunchKernelGGL(k_binscatter, dim3(BINBLK), dim3(256), 0, stream, bucket, bb, order);

    hipFuncSetAttribute(reinterpret_cast<const void*>(k_main),
                        hipFuncAttributeMaxDynamicSharedMemorySize, LDS_BYTES);
    hipLaunchKernelGGL(k_main, dim3(MAXBLK), dim3(NT), LDS_BYTES, stream,
                       stm, nstm, Wacc, bacc, b1, W2, b2, W3, b3,
                       waccF, w1F, cnt, basep, order, blkmap, out);
}

// Round 7
// 231.682 us; speedup vs baseline: 1.3283x; 1.3283x over previous
//
#include <hip/hip_runtime.h>

typedef _Float16 f16;
typedef f16 f16x8 __attribute__((ext_vector_type(8)));
typedef float f32x4 __attribute__((ext_vector_type(4)));
typedef float f32x16 __attribute__((ext_vector_type(16)));

#define BATCH   32768
#define NF      162
#define ACCH    1024      // hidden accumulator width (without psqt)
#define KSL     192       // K padded to 192 halfs
#define NKS2    12        // 32x32x16 K-steps per 192
#define NB      8
#define DIVQ    20
#define TM      64        // rows per block
#define NT      512       // threads per block
#define NCH     128       // hidden chunk
#define NCHUNK  (ACCH/NCH) // 8
#define MAXBLK  (BATCH/TM + NB - 1)   // 519

// binning partition
#define BINBLK  256
#define RPB     (BATCH / BINBLK)      // 128 rows per binning block

// workspace layout (bytes)
#define WS_WACC16   0
#define WS_W116     (WS_WACC16 + ACCH*KSL*2)       // 393216
#define WS_BUCKET   (WS_W116 + 256*2048*2)         // 1441792
#define WS_ORDER    (WS_BUCKET + BATCH*4)          // 1572864
#define WS_CNT      (WS_ORDER + BATCH*4)           // 1703936
#define WS_BASE     (WS_CNT + 64)
#define WS_PART     (WS_BASE + 64)                 // BINBLK*8 ints
#define WS_BB       (WS_PART + BINBLK*8*4)         // BINBLK*8 ints
#define WS_BLKMAP   WS_PART                        // reuse: part dead after binsetup reads it

// LDS: Xb 16384 (h1s/h2s alias) + psq 256
#define LDS_BYTES   16640

// ---------------- fused prep + binning ----------------
// blocks [0,256): bucket per row + per-block histogram (no global atomics)
// blocks [256,1024): weights -> f16 fragment-major layouts
// waccF (32x32x16 B-frag): u16 idx = (((c*12+ks)*2 + kh)*128 + n)*8 + e
//   value = Wacc[c*128+n][k], k = ks*16 + kh*8 + e (0 if k>=NF)
// w1F (16x16x32 B-frag): u16 idx = ((((bkt*2+s)*8+c)*16 + ks*4 + l4)*32 + n)*8 + e
//   value = W1[bkt*32+n][s*1024 + c*128 + ks*32 + l4*8 + e]
__global__ __launch_bounds__(512) void k_prepbin(const float* __restrict__ stm,
                                                 const float* __restrict__ Wacc,
                                                 const float* __restrict__ W1,
                                                 int* __restrict__ bucket,
                                                 int* __restrict__ part,
                                                 f16* __restrict__ waccF,
                                                 f16* __restrict__ w1F)
{
    if (blockIdx.x < BINBLK) {
        __shared__ int hist[NB];
        int tid = threadIdx.x;
        if (tid < NB) hist[tid] = 0;
        __syncthreads();
        int wv = tid >> 6, ln = tid & 63;
        int rowbase = blockIdx.x * RPB + wv * (RPB / 8);   // 16 rows per wave
        for (int i = 0; i < RPB / 8; i++) {
            int row = rowbase + i;
            const float* rp = stm + (long)row * NF;
            float s = 0.f;
            for (int k = ln; k < NF; k += 64) s += rp[k];
            for (int off = 32; off > 0; off >>= 1) s += __shfl_down(s, off);
            if (ln == 0) {
                int pc = (int)(s + 0.5f);
                int b = pc / DIVQ; if (b > NB - 1) b = NB - 1;
                bucket[row] = b;
                atomicAdd(&hist[b], 1);
            }
        }
        __syncthreads();
        if (tid < NB) part[blockIdx.x * NB + tid] = hist[tid];
    } else {
        int tid = (blockIdx.x - BINBLK) * blockDim.x + threadIdx.x;
        int stride = (gridDim.x - BINBLK) * blockDim.x;
        // waccF: dest-linear (small, 384 KB)
        for (int t = tid; t < ACCH * KSL; t += stride) {
            int e = t & 7, f = t >> 3;
            int n = f & 127, g = f >> 7;
            int kh = g & 1, h = g >> 1;
            int ks = h % NKS2, c = h / NKS2;
            int k = ks * 16 + kh * 8 + e;
            int row = c * 128 + n;
            waccF[t] = (f16)((k < NF) ? Wacc[row * NF + k] : 0.f);
        }
        // w1F: source-linear coalesced float4 reads, scattered 8B writes
        for (int t4 = tid; t4 < 256 * 2048 / 4; t4 += stride) {
            int t = t4 * 4;
            float4 v = *(const float4*)(W1 + t);
            int n_g = t >> 11, k = t & 2047;
            int bkt = n_g >> 5, n = n_g & 31;
            int s = k >> 10, c = (k >> 7) & 7, ks = (k >> 5) & 3, l4 = (k >> 3) & 3;
            int e = k & 7;   // 0 or 4
            long base = (((((long)(bkt * 2 + s) * 8 + c) * 16 + ks * 4 + l4) * 32 + n) * 8) + e;
            w1F[base + 0] = (f16)v.x;
            w1F[base + 1] = (f16)v.y;
            w1F[base + 2] = (f16)v.z;
            w1F[base + 3] = (f16)v.w;
        }
    }
}

// 8 waves, one per bucket: parallel prefix over 256 per-block partials
__global__ __launch_bounds__(512) void k_binsetup(const int* __restrict__ part,
                                                  int* __restrict__ cnt,
                                                  int* __restrict__ base,
                                                  int* __restrict__ bb,
                                                  int* __restrict__ blkmap)
{
    __shared__ int tot[NB], bas[NB], tstart[NB + 1];
    int tid = threadIdx.x;
    int wv = tid >> 6, ln = tid & 63;
    int b = wv;
    int v0 = part[(ln * 4 + 0) * NB + b];
    int v1 = part[(ln * 4 + 1) * NB + b];
    int v2 = part[(ln * 4 + 2) * NB + b];
    int v3 = part[(ln * 4 + 3) * NB + b];
    int s = v0 + v1 + v2 + v3;
    int inc = s;
    for (int off = 1; off < 64; off <<= 1) {
        int n = __shfl_up(inc, off);
        if (ln >= off) inc += n;
    }
    int exc = inc - s;
    if (ln == 63) tot[b] = inc;
    __syncthreads();
    if (tid == 0) {
        int a = 0;
        for (int q = 0; q < NB; q++) { bas[q] = a; base[q] = a; a += tot[q]; }
        int t = 0;
        for (int q = 0; q < NB; q++) { tstart[q] = t; t += (tot[q] + TM - 1) / TM; }
        tstart[NB] = t;
        for (int q = 0; q < NB; q++) cnt[q] = tot[q];
    }
    __syncthreads();
    int run = exc + bas[b];
    bb[(ln * 4 + 0) * NB + b] = run; run += v0;
    bb[(ln * 4 + 1) * NB + b] = run; run += v1;
    bb[(ln * 4 + 2) * NB + b] = run; run += v2;
    bb[(ln * 4 + 3) * NB + b] = run;
    for (int i = tid; i < MAXBLK; i += 512) {
        int v = -1;
        for (int q = 0; q < NB; q++)
            if (i >= tstart[q] && i < tstart[q + 1]) v = q | ((i - tstart[q]) << 4);
        blkmap[i] = v;
    }
}

__global__ __launch_bounds__(256) void k_binscatter(const int* __restrict__ bucket,
                                                    const int* __restrict__ bb,
                                                    int* __restrict__ order)
{
    __shared__ int lcur[NB];
    int tid = threadIdx.x;
    if (tid < NB) lcur[tid] = bb[blockIdx.x * NB + tid];
    __syncthreads();
    int blkstart = blockIdx.x * RPB;
    for (int i = tid; i < RPB; i += 256) {
        int row = blkstart + i;
        int b = bucket[row];
        int pos = atomicAdd(&lcur[b], 1);
        order[pos] = row;
    }
}

// ---------------- fused main kernel ----------------
// Phase 1: A-panel (features) held in registers across all chunks; B-frags from global.
// __launch_bounds__(512, 2): empirically hipcc treats 2nd arg as min BLOCKS/CU
// (4->64 VGPR cap, 5->48, 6->40). 2 blocks/CU -> 128 VGPR cap; natural demand
// ~95-100 (af[12]=48 + acc16 + temps) fits -> no spill + 2-block co-residency.
__global__ __launch_bounds__(NT, 2) void k_main(
    const float* __restrict__ stm, const float* __restrict__ nstm,
    const float* __restrict__ Wacc, const float* __restrict__ bacc,
    const float* __restrict__ b1, const float* __restrict__ W2,
    const float* __restrict__ b2, const float* __restrict__ W3,
    const float* __restrict__ b3,
    const f16* __restrict__ waccF, const f16* __restrict__ w1F,
    const int* __restrict__ cnt, const int* __restrict__ base,
    const int* __restrict__ order, const int* __restrict__ blkmap,
    float* __restrict__ out)
{
    int bm = blkmap[blockIdx.x];
    if (bm < 0) return;
    int bkt = bm & 15, tile = bm >> 4;
    int rowbase = base[bkt] + tile * TM;
    int nrows = cnt[bkt] - tile * TM; if (nrows > TM) nrows = TM;

    extern __shared__ __align__(16) char lds_raw[];
    f16* Xb   = (f16*)lds_raw;                      // [64][128] swizzled
    f16* h1s  = (f16*)lds_raw;                      // [64][40], aliases Xb (after last phase2)
    f16* h2s  = (f16*)(lds_raw + TM * 40 * 2);      // [64][40], aliases Xb
    float* psq = (float*)(lds_raw + TM * NCH * 2);  // [64]

    int tid = threadIdx.x;
    int wv = tid >> 6, ln = tid & 63;
    int l15 = ln & 15, l4 = ln >> 4;
    int l31 = ln & 31, kh = ln >> 5;

    // wave tile assignment
    int wr = wv & 1;    // phase1 row-half (rows wr*32..+32)
    int wc = wv >> 1;   // phase1 col-quarter (cols wc*32..+32)
    int mt = wv >> 1;   // phase2/3: M-tile 0..3
    int nh = wv & 1;    // phase2/3: N-half 0..1

    int myrow = wr * 32 + l31;
    int rowclamp = (myrow < nrows) ? myrow : (nrows - 1);
    int rowidx = order[rowbase + rowclamp];

    int colc = wc * 32 + l31;   // col within chunk (0..127)

    float bb1 = b1[bkt * 32 + nh * 16 + l15];
    f32x4 h1acc; h1acc[0] = h1acc[1] = h1acc[2] = h1acc[3] = bb1;

    const float* psqw = Wacc + (long)ACCH * NF;   // psqt weight row (fp32)
    const f16x8* wfr  = (const f16x8*)waccF;
    const f16x8* w1fr = (const f16x8*)w1F;

    for (int s = 0; s < 2; s++) {
        const float* src = s ? nstm : stm;
        const float* rp = src + (long)rowidx * NF;

        // ---- load A-panel (12 x f16x8 per lane) direct from global + psqt on the fly ----
        f16x8 af[NKS2];
        float pp = 0.f;
        #pragma unroll
        for (int ks = 0; ks < NKS2; ks++) {
            int k0 = ks * 16 + kh * 8;
            float v0=0.f,v1=0.f,v2=0.f,v3=0.f,v4=0.f,v5=0.f,v6=0.f,v7=0.f;
            if (k0 <= 152) {
                float2 a0 = *(const float2*)(rp + k0);
                float2 a1 = *(const float2*)(rp + k0 + 2);
                float2 a2 = *(const float2*)(rp + k0 + 4);
                float2 a3 = *(const float2*)(rp + k0 + 6);
                v0=a0.x; v1=a0.y; v2=a1.x; v3=a1.y;
                v4=a2.x; v5=a2.y; v6=a3.x; v7=a3.y;
                float4 pa = *(const float4*)(psqw + k0);
                float4 pb = *(const float4*)(psqw + k0 + 4);
                pp += v0*pa.x + v1*pa.y + v2*pa.z + v3*pa.w
                    + v4*pb.x + v5*pb.y + v6*pb.z + v7*pb.w;
            } else if (k0 == 160) {
                float2 a0 = *(const float2*)(rp + 160);
                v0 = a0.x; v1 = a0.y;
                pp += v0*psqw[160] + v1*psqw[161];
            }
            f16x8 h;
            h[0]=(f16)v0; h[1]=(f16)v1; h[2]=(f16)v2; h[3]=(f16)v3;
            h[4]=(f16)v4; h[5]=(f16)v5; h[6]=(f16)v6; h[7]=(f16)v7;
            af[ks] = h;
        }
        pp += __shfl_xor(pp, 32);          // combine kh halves: full row dot
        if (wv < 2 && ln < 32) {           // one wave pair owns psq writes
            if (s) psq[wr * 32 + l31] -= 0.5f * pp;
            else   psq[wr * 32 + l31]  = 0.5f * pp;
        }

        for (int c = 0; c < NCHUNK; c++) {
            // ---- phase 1: 32x32 MFMA, A from regs, B from global (L2-hot) ----
            float bias = bacc[c * NCH + colc];
            f32x16 acc;
            #pragma unroll
            for (int q = 0; q < 16; q++) acc[q] = bias;

            const f16x8* wp = wfr + ((c * NKS2) * 2 + kh) * 128 + colc;
            #pragma unroll
            for (int ks = 0; ks < NKS2; ks++) {
                f16x8 bf = wp[ks * 256];
                acc = __builtin_amdgcn_mfma_f32_32x32x16_f16(af[ks], bf, acc, 0, 0, 0);
            }
            __syncthreads();  // Xb free (phase2 readers of prev chunk done)
            // epilogue: clip^2 -> Xb (f16, swizzled)
            #pragma unroll
            for (int reg = 0; reg < 16; reg++) {
                int rr = wr * 32 + 4 * kh + (reg & 3) + 8 * (reg >> 2);
                float v = acc[reg];
                v = fminf(fmaxf(v, 0.f), 1.f);
                v = v * v;
                Xb[rr * NCH + ((((colc >> 3) ^ (rr & 7)) << 3) | (colc & 7))] = (f16)v;
            }
            __syncthreads();  // Xb ready

            // ---- phase 2: h1 += act_chunk @ W1_chunk^T (16x16), B-frags from global ----
            const f16x8* w1p = w1fr + ((bkt * 2 + s) * 8 + c) * 512;
            #pragma unroll
            for (int ks = 0; ks < NCH / 32; ks++) {
                int s0 = ks * 4 + l4;
                int row = mt * 16 + l15;
                f16x8 a = *(const f16x8*)(Xb + row * NCH + ((s0 ^ (row & 7)) << 3));
                f16x8 b = w1p[s0 * 32 + nh * 16 + l15];
                h1acc = __builtin_amdgcn_mfma_f32_16x16x32_f16(a, b, h1acc, 0, 0, 0);
            }
        }
    }

    __syncthreads();  // all phase2 reads of Xb done before h1s overwrite (alias)

    // ---- h1 finalize: clip [0,1] -> h1s ----
    #pragma unroll
    for (int jr = 0; jr < 4; jr++) {
        int row = mt * 16 + l4 * 4 + jr;
        int col = nh * 16 + l15;
        float v = fminf(fmaxf(h1acc[jr], 0.f), 1.f);
        h1s[row * 40 + col] = (f16)v;
    }
    __syncthreads();

    // ---- layer 3: h2 = clip(h1 @ W2_b^T + b2, 0, 1); W2 frag direct from global ----
    {
        int nn = nh * 16 + l15;
        const float* w2r = W2 + (bkt * 32 + nn) * 32;
        float4 wa = *(const float4*)(w2r + l4 * 8);
        float4 wb = *(const float4*)(w2r + l4 * 8 + 4);
        f16x8 bfr;
        bfr[0]=(f16)wa.x; bfr[1]=(f16)wa.y; bfr[2]=(f16)wa.z; bfr[3]=(f16)wa.w;
        bfr[4]=(f16)wb.x; bfr[5]=(f16)wb.y; bfr[6]=(f16)wb.z; bfr[7]=(f16)wb.w;
        int row = mt * 16 + l15;
        f16x8 a = *(const f16x8*)(h1s + row * 40 + l4 * 8);
        float bb2 = b2[bkt * 32 + nn];
        f32x4 acc2; acc2[0] = acc2[1] = acc2[2] = acc2[3] = bb2;
        acc2 = __builtin_amdgcn_mfma_f32_16x16x32_f16(a, bfr, acc2, 0, 0, 0);
        #pragma unroll
        for (int jr = 0; jr < 4; jr++) {
            int r2 = mt * 16 + l4 * 4 + jr;
            float v = fminf(fmaxf(acc2[jr], 0.f), 1.f);
            h2s[r2 * 40 + nn] = (f16)v;
        }
    }
    __syncthreads();

    // ---- layer 4 + psqt -> output ----
    if (tid < nrows) {
        const float* w3r = W3 + bkt * 32;
        float o = b3[bkt] + psq[tid];
        #pragma unroll 8
        for (int n = 0; n < 32; n++) o += (float)h2s[tid * 40 + n] * w3r[n];
        out[order[rowbase + tid]] = o;
    }
}

// ---------------- launcher ----------------
extern "C" void kernel_launch(void* const* d_in, const int* in_sizes, int n_in,
                              void* d_out, int out_size, void* d_ws, size_t ws_size,
                              hipStream_t stream)
{
    (void)in_sizes; (void)n_in; (void)out_size; (void)ws_size;
    const float* stm  = (const float*)d_in[0];
    const float* nstm = (const float*)d_in[1];
    const float* Wacc = (const float*)d_in[2];
    const float* bacc = (const float*)d_in[3];
    const float* W1   = (const float*)d_in[4];
    const float* b1   = (const float*)d_in[5];
    const float* W2   = (const float*)d_in[6];
    const float* b2   = (const float*)d_in[7];
    const float* W3   = (const float*)d_in[8];
    const float* b3   = (const float*)d_in[9];
    float* out = (float*)d_out;

    char* ws = (char*)d_ws;
    f16* waccF  = (f16*)(ws + WS_WACC16);
    f16* w1F    = (f16*)(ws + WS_W116);
    int* bucket = (int*)(ws + WS_BUCKET);
    int* order  = (int*)(ws + WS_ORDER);
    int* cnt    = (int*)(ws + WS_CNT);
    int* basep  = (int*)(ws + WS_BASE);
    int* part   = (int*)(ws + WS_PART);
    int* bb     = (int*)(ws + WS_BB);
    int* blkmap = (int*)(ws + WS_BLKMAP);   // aliases part (dead after binsetup)

    hipLaunchKernelGGL(k_prepbin, dim3(1024), dim3(512), 0, stream,
                       stm, Wacc, W1, bucket, part, waccF, w1F);
    hipLaunchKernelGGL(k_binsetup, dim3(1), dim3(512), 0, stream, part, cnt, basep, bb, blkmap);
    hipLaunchKernelGGL(k_binscatter, dim3(BINBLK), dim3(256), 0, stream, bucket, bb, order);

    hipFuncSetAttribute(reinterpret_cast<const void*>(k_main),
                        hipFuncAttributeMaxDynamicSharedMemorySize, LDS_BYTES);
    hipLaunchKernelGGL(k_main, dim3(MAXBLK), dim3(NT), LDS_BYTES, stream,
                       stm, nstm, Wacc, bacc, b1, W2, b2, W3, b3,
                       waccF, w1F, cnt, basep, order, blkmap, out);
}